// Round 4
// baseline (2248.454 us; speedup 1.0000x reference)
//
#include <hip/hip_runtime.h>
#include <hip/hip_bf16.h>
#include <math.h>

#define N_OBJ 4096
#define IN_DIM 1024
#define EMB_D 200
#define HID 1024
#define NCLS 151
#define IN_SZ 1224      // IN_DIM + EMB_D
#define NEMB 152        // NCLS + 1 embedding rows
#define R5 5120         // px(1024) + iou(3072) + f(1024) pre-activation rows
#define RH 4096         // h-dependent rows (iou 3072 + f 1024)
#define MAXLVL 32

typedef __attribute__((ext_vector_type(8))) short bf16x8;
typedef __attribute__((ext_vector_type(4))) float f32x4;

__device__ __forceinline__ float sigf(float x) { return 1.f / (1.f + expf(-x)); }

// split fp32 into hi+lo bf16 (RNE both stages); hi+lo carries ~18 mantissa bits
__device__ __forceinline__ void split2(float x, ushort& hi, ushort& lo) {
    unsigned u = __float_as_uint(x);
    unsigned r = u + 0x7FFFu + ((u >> 16) & 1u);
    hi = (ushort)(r >> 16);
    float rem = x - __uint_as_float(r & 0xFFFF0000u);
    unsigned u2 = __float_as_uint(rem);
    unsigned r2 = u2 + 0x7FFFu + ((u2 >> 16) & 1u);
    lo = (ushort)(r2 >> 16);
}

// ---------------------------------------------------------------------------
// Kernel 1: depth per step, bucket steps by level; also zero the zpad region.
// ---------------------------------------------------------------------------
__global__ __launch_bounds__(1024)
void build_levels(const int* __restrict__ parent_pos,
                  int* __restrict__ level_nodes,
                  int* __restrict__ level_start,
                  ushort* __restrict__ zpad)
{
    __shared__ int dep[N_OBJ];
    __shared__ int par[N_OBJ];
    __shared__ int cnt[MAXLVL];
    __shared__ int offs[MAXLVL];
    __shared__ int base[MAXLVL + 1];
    __shared__ int done;
    const int tid = threadIdx.x;

    if (tid < 1024) zpad[tid] = 0;

    for (int t = tid; t < N_OBJ; t += 1024) {
        int p = parent_pos[t];
        par[t] = p;
        dep[t] = (p < 0) ? 0 : -1;
    }
    for (int l = tid; l < MAXLVL; l += 1024) { cnt[l] = 0; offs[l] = 0; }
    __syncthreads();

    for (int it = 0; it < 64; ++it) {
        if (tid == 0) done = 1;
        __syncthreads();
        for (int t = tid; t < N_OBJ; t += 1024) {
            if (dep[t] < 0) {
                int dp = dep[par[t]];
                if (dp >= 0) dep[t] = dp + 1;
                else done = 0;
            }
        }
        __syncthreads();
        int d = done;
        __syncthreads();
        if (d) break;
    }

    for (int t = tid; t < N_OBJ; t += 1024) {
        int d = dep[t];
        if (d < 0 || d >= MAXLVL) d = MAXLVL - 1;  // safety clamp
        dep[t] = d;
        atomicAdd(&cnt[d], 1);
    }
    __syncthreads();
    if (tid == 0) {
        base[0] = 0;
        for (int l = 0; l < MAXLVL; ++l) base[l + 1] = base[l] + cnt[l];
    }
    __syncthreads();
    for (int t = tid; t < N_OBJ; t += 1024) {
        int d = dep[t];
        int pos = base[d] + atomicAdd(&offs[d], 1);
        level_nodes[pos] = t;
    }
    for (int l = tid; l <= MAXLVL; l += 1024) level_start[l] = base[l];
}

// ---------------------------------------------------------------------------
// Kernel 2: Xemb[e][r] = W_row_r[:, 1024:1224] @ embed_W[e] + (all biases)
// ---------------------------------------------------------------------------
__global__ __launch_bounds__(256)
void xemb_kernel(const float* __restrict__ embed_W,
                 const float* __restrict__ W_px,
                 const float* __restrict__ W_ioux,
                 const float* __restrict__ W_fx,
                 const float* __restrict__ b_px,
                 const float* __restrict__ b_ioux,
                 const float* __restrict__ b_iouh,
                 const float* __restrict__ b_fx,
                 const float* __restrict__ b_fh,
                 float* __restrict__ Xemb)
{
    __shared__ float e_s[EMB_D];
    const int e = blockIdx.x;
    const int r = blockIdx.y * 256 + threadIdx.x;
    for (int k = threadIdx.x; k < EMB_D; k += 256) e_s[k] = embed_W[(size_t)e * EMB_D + k];
    __syncthreads();

    const float* wrow;
    float bias;
    if (r < HID) {
        wrow = W_px + (size_t)r * IN_SZ;
        bias = b_px[r];
    } else if (r < 4 * HID) {
        wrow = W_ioux + (size_t)(r - HID) * IN_SZ;
        bias = b_ioux[r - HID] + b_iouh[r - HID];
    } else {
        wrow = W_fx + (size_t)(r - 4 * HID) * IN_SZ;
        bias = b_fx[r - 4 * HID] + b_fh[r - 4 * HID];
    }

    float s = bias;
    for (int k = 0; k < EMB_D; ++k) s += wrow[IN_DIM + k] * e_s[k];
    Xemb[(size_t)e * R5 + r] = s;
}

// ---------------------------------------------------------------------------
// One-time split-conversion kernels (fp32 -> hi/lo bf16 pairs)
// ---------------------------------------------------------------------------
__global__ __launch_bounds__(256)
void convert_wh(const float* __restrict__ W_iouh, const float* __restrict__ W_fh,
                ushort* __restrict__ Whh, ushort* __restrict__ Whl)
{
    const int idx = (blockIdx.x * 256 + threadIdx.x) * 4;   // over RH*HID
    const int row = idx >> 10, k = idx & 1023;
    const float* src = (row < 3 * HID) ? (W_iouh + (size_t)row * HID + k)
                                       : (W_fh + (size_t)(row - 3 * HID) * HID + k);
    float4 v = *(const float4*)src;
    ushort4 hi, lo;
    split2(v.x, hi.x, lo.x); split2(v.y, hi.y, lo.y);
    split2(v.z, hi.z, lo.z); split2(v.w, hi.w, lo.w);
    *(ushort4*)(Whh + (size_t)row * HID + k) = hi;
    *(ushort4*)(Whl + (size_t)row * HID + k) = lo;
}

__global__ __launch_bounds__(256)
void convert_wx(const float* __restrict__ W_px, const float* __restrict__ W_ioux,
                const float* __restrict__ W_fx,
                ushort* __restrict__ Wxh, ushort* __restrict__ Wxl)
{
    const int idx = (blockIdx.x * 256 + threadIdx.x) * 4;   // over R5*IN_DIM
    const int row = idx >> 10, k = idx & 1023;
    const float* src;
    if (row < HID)          src = W_px   + (size_t)row * IN_SZ + k;
    else if (row < 4 * HID) src = W_ioux + (size_t)(row - HID) * IN_SZ + k;
    else                    src = W_fx   + (size_t)(row - 4 * HID) * IN_SZ + k;
    float4 v = *(const float4*)src;
    ushort4 hi, lo;
    split2(v.x, hi.x, lo.x); split2(v.y, hi.y, lo.y);
    split2(v.z, hi.z, lo.z); split2(v.w, hi.w, lo.w);
    *(ushort4*)(Wxh + (size_t)row * IN_DIM + k) = hi;
    *(ushort4*)(Wxl + (size_t)row * IN_DIM + k) = lo;
}

__global__ __launch_bounds__(256)
void convert_f(const float* __restrict__ features, const int* __restrict__ proc_order,
               ushort* __restrict__ Fh, ushort* __restrict__ Fl)
{
    const int idx = (blockIdx.x * 256 + threadIdx.x) * 4;   // over N_OBJ*IN_DIM
    const int t = idx >> 10, k = idx & 1023;
    const float* src = features + (size_t)proc_order[t] * IN_DIM + k;
    float4 v = *(const float4*)src;
    ushort4 hi, lo;
    split2(v.x, hi.x, lo.x); split2(v.y, hi.y, lo.y);
    split2(v.z, hi.z, lo.z); split2(v.w, hi.w, lo.w);
    *(ushort4*)(Fh + (size_t)t * IN_DIM + k) = hi;
    *(ushort4*)(Fl + (size_t)t * IN_DIM + k) = lo;
}

// ---------------------------------------------------------------------------
// Kernel 3 (ONCE): x-part GEMM via split-bf16 MFMA.
//   Hbuf[t][r] = Wx_r . feat[t]   (t = step; features pre-gathered into Fh/Fl)
// 128x128 tile, K-chunk 64, 4 waves (2x2), wave tile 64x64 of 16x16x32 frags.
// ---------------------------------------------------------------------------
__global__ __launch_bounds__(256)
void xgemm_mfma(const ushort* __restrict__ Fh, const ushort* __restrict__ Fl,
                const ushort* __restrict__ Wxh, const ushort* __restrict__ Wxl,
                float* __restrict__ Hbuf)
{
    // 32 m-blocks x 40 n-blocks, 8x8 supertiles for L2/L3 locality
    const int bid = blockIdx.x;
    const int sup = bid >> 6, within = bid & 63;
    const int bm = (sup & 3) * 8 + (within & 7);
    const int bn = (sup >> 2) * 8 + (within >> 3);

    __shared__ ushort Ah[128][72], Al[128][72], Bh[128][72], Bl[128][72];

    const int tid = threadIdx.x;
    const int lane = tid & 63;
    const int wid = tid >> 6;
    const int wm = wid & 1, wn = wid >> 1;

    // staging: thread covers row = tid>>1 (0..127), kq = tid&1 (32 shorts = 64B)
    const int srow = tid >> 1, skq = tid & 1;
    const ushort* gAh = Fh  + (size_t)(bm * 128 + srow) * IN_DIM + skq * 32;
    const ushort* gAl = Fl  + (size_t)(bm * 128 + srow) * IN_DIM + skq * 32;
    const ushort* gBh = Wxh + (size_t)(bn * 128 + srow) * IN_DIM + skq * 32;
    const ushort* gBl = Wxl + (size_t)(bn * 128 + srow) * IN_DIM + skq * 32;

    f32x4 acc[4][4];
    #pragma unroll
    for (int i = 0; i < 4; ++i)
        #pragma unroll
        for (int j = 0; j < 4; ++j)
            acc[i][j] = (f32x4){0.f, 0.f, 0.f, 0.f};

    uint4 rA0[4], rA1[4], rB0[4], rB1[4];
    #pragma unroll
    for (int j = 0; j < 4; ++j) {
        rA0[j] = *(const uint4*)(gAh + j * 8);
        rA1[j] = *(const uint4*)(gAl + j * 8);
        rB0[j] = *(const uint4*)(gBh + j * 8);
        rB1[j] = *(const uint4*)(gBl + j * 8);
    }

    for (int kc = 0; kc < IN_DIM / 64; ++kc) {
        __syncthreads();   // previous chunk's frag reads done
        #pragma unroll
        for (int j = 0; j < 4; ++j) {
            *(uint4*)&Ah[srow][skq * 32 + j * 8] = rA0[j];
            *(uint4*)&Al[srow][skq * 32 + j * 8] = rA1[j];
            *(uint4*)&Bh[srow][skq * 32 + j * 8] = rB0[j];
            *(uint4*)&Bl[srow][skq * 32 + j * 8] = rB1[j];
        }
        __syncthreads();
        if (kc + 1 < IN_DIM / 64) {
            const int kt = (kc + 1) * 64;
            #pragma unroll
            for (int j = 0; j < 4; ++j) {
                rA0[j] = *(const uint4*)(gAh + kt + j * 8);
                rA1[j] = *(const uint4*)(gAl + kt + j * 8);
                rB0[j] = *(const uint4*)(gBh + kt + j * 8);
                rB1[j] = *(const uint4*)(gBl + kt + j * 8);
            }
        }
        const int g = lane >> 4;
        #pragma unroll
        for (int s = 0; s < 2; ++s) {
            bf16x8 fah[4], fal[4], fbh[4], fbl[4];
            #pragma unroll
            for (int mi = 0; mi < 4; ++mi) {
                int row = wm * 64 + mi * 16 + (lane & 15);
                int o = row * 72 + s * 32 + g * 8;
                fah[mi] = *(const bf16x8*)(&Ah[0][0] + o);
                fal[mi] = *(const bf16x8*)(&Al[0][0] + o);
            }
            #pragma unroll
            for (int ni = 0; ni < 4; ++ni) {
                int row = wn * 64 + ni * 16 + (lane & 15);
                int o = row * 72 + s * 32 + g * 8;
                fbh[ni] = *(const bf16x8*)(&Bh[0][0] + o);
                fbl[ni] = *(const bf16x8*)(&Bl[0][0] + o);
            }
            #pragma unroll
            for (int mi = 0; mi < 4; ++mi)
                #pragma unroll
                for (int ni = 0; ni < 4; ++ni) {
                    acc[mi][ni] = __builtin_amdgcn_mfma_f32_16x16x32_bf16(fah[mi], fbh[ni], acc[mi][ni], 0, 0, 0);
                    acc[mi][ni] = __builtin_amdgcn_mfma_f32_16x16x32_bf16(fah[mi], fbl[ni], acc[mi][ni], 0, 0, 0);
                    acc[mi][ni] = __builtin_amdgcn_mfma_f32_16x16x32_bf16(fal[mi], fbh[ni], acc[mi][ni], 0, 0, 0);
                }
        }
    }

    const int r4 = (lane >> 4) * 4;
    #pragma unroll
    for (int mi = 0; mi < 4; ++mi)
        #pragma unroll
        for (int ni = 0; ni < 4; ++ni) {
            const int col = bn * 128 + wn * 64 + ni * 16 + (lane & 15);
            #pragma unroll
            for (int r = 0; r < 4; ++r) {
                const int t = bm * 128 + wm * 64 + mi * 16 + r4 + r;
                Hbuf[(size_t)t * R5 + col] = acc[mi][ni][r];
            }
        }
}

// ---------------------------------------------------------------------------
// Kernel 4 (per level): Hbuf[t][1024+r] += Wh_r . h[parent(t)]  via split-bf16
// MFMA. 64 nodes x 128 rows, K-chunk 64, 4 waves (2x2), wave tile 32x64.
// ---------------------------------------------------------------------------
__global__ __launch_bounds__(256)
void hgemm_mfma(int lvl,
                const int* __restrict__ level_start,
                const int* __restrict__ level_nodes,
                const int* __restrict__ parent_pos,
                const ushort* __restrict__ hh, const ushort* __restrict__ hl,
                const ushort* __restrict__ Whh, const ushort* __restrict__ Whl,
                const ushort* __restrict__ zpad,
                float* __restrict__ Hbuf)
{
    const int s0 = level_start[lvl];
    const int n  = level_start[lvl + 1] - s0;
    const int bm = blockIdx.y;
    if (bm * 64 >= n) return;            // uniform exit before any barrier
    const int bn = blockIdx.x;           // 0..31 row-blocks of 128
    const int tid = threadIdx.x;
    const int lane = tid & 63;
    const int wid = tid >> 6;
    const int wm = wid & 1, wn = wid >> 1;

    __shared__ ushort Ah[64][72], Al[64][72], Bh[128][72], Bl[128][72];
    __shared__ int s_node[64], s_par[64];

    if (tid < 64) {
        int m = bm * 64 + tid;
        if (m < n) {
            int t = level_nodes[s0 + m];
            s_node[tid] = t;
            s_par[tid]  = parent_pos[t];
        } else { s_node[tid] = -1; s_par[tid] = -1; }
    }
    __syncthreads();

    const int arow = tid >> 2, akq = tid & 3;   // 64 rows x 16 shorts (32B)
    const int par = s_par[arow];
    const ushort* gAh = (par >= 0 ? hh + (size_t)par * HID : zpad) + akq * 16;
    const ushort* gAl = (par >= 0 ? hl + (size_t)par * HID : zpad) + akq * 16;
    const int brow = tid >> 1, bkq = tid & 1;   // 128 rows x 32 shorts (64B)
    const ushort* gBh = Whh + (size_t)(bn * 128 + brow) * HID + bkq * 32;
    const ushort* gBl = Whl + (size_t)(bn * 128 + brow) * HID + bkq * 32;

    f32x4 acc[2][4];
    #pragma unroll
    for (int i = 0; i < 2; ++i)
        #pragma unroll
        for (int j = 0; j < 4; ++j)
            acc[i][j] = (f32x4){0.f, 0.f, 0.f, 0.f};

    uint4 rA0[2], rA1[2], rB0[4], rB1[4];
    #pragma unroll
    for (int j = 0; j < 2; ++j) {
        rA0[j] = *(const uint4*)(gAh + j * 8);
        rA1[j] = *(const uint4*)(gAl + j * 8);
    }
    #pragma unroll
    for (int j = 0; j < 4; ++j) {
        rB0[j] = *(const uint4*)(gBh + j * 8);
        rB1[j] = *(const uint4*)(gBl + j * 8);
    }

    for (int kc = 0; kc < HID / 64; ++kc) {
        __syncthreads();
        #pragma unroll
        for (int j = 0; j < 2; ++j) {
            *(uint4*)&Ah[arow][akq * 16 + j * 8] = rA0[j];
            *(uint4*)&Al[arow][akq * 16 + j * 8] = rA1[j];
        }
        #pragma unroll
        for (int j = 0; j < 4; ++j) {
            *(uint4*)&Bh[brow][bkq * 32 + j * 8] = rB0[j];
            *(uint4*)&Bl[brow][bkq * 32 + j * 8] = rB1[j];
        }
        __syncthreads();
        if (kc + 1 < HID / 64) {
            const int kt = (kc + 1) * 64;
            #pragma unroll
            for (int j = 0; j < 2; ++j) {
                rA0[j] = *(const uint4*)(gAh + kt + j * 8);
                rA1[j] = *(const uint4*)(gAl + kt + j * 8);
            }
            #pragma unroll
            for (int j = 0; j < 4; ++j) {
                rB0[j] = *(const uint4*)(gBh + kt + j * 8);
                rB1[j] = *(const uint4*)(gBl + kt + j * 8);
            }
        }
        const int g = lane >> 4;
        #pragma unroll
        for (int s = 0; s < 2; ++s) {
            bf16x8 fah[2], fal[2], fbh[4], fbl[4];
            #pragma unroll
            for (int mi = 0; mi < 2; ++mi) {
                int row = wm * 32 + mi * 16 + (lane & 15);
                int o = row * 72 + s * 32 + g * 8;
                fah[mi] = *(const bf16x8*)(&Ah[0][0] + o);
                fal[mi] = *(const bf16x8*)(&Al[0][0] + o);
            }
            #pragma unroll
            for (int ni = 0; ni < 4; ++ni) {
                int row = wn * 64 + ni * 16 + (lane & 15);
                int o = row * 72 + s * 32 + g * 8;
                fbh[ni] = *(const bf16x8*)(&Bh[0][0] + o);
                fbl[ni] = *(const bf16x8*)(&Bl[0][0] + o);
            }
            #pragma unroll
            for (int mi = 0; mi < 2; ++mi)
                #pragma unroll
                for (int ni = 0; ni < 4; ++ni) {
                    acc[mi][ni] = __builtin_amdgcn_mfma_f32_16x16x32_bf16(fah[mi], fbh[ni], acc[mi][ni], 0, 0, 0);
                    acc[mi][ni] = __builtin_amdgcn_mfma_f32_16x16x32_bf16(fah[mi], fbl[ni], acc[mi][ni], 0, 0, 0);
                    acc[mi][ni] = __builtin_amdgcn_mfma_f32_16x16x32_bf16(fal[mi], fbh[ni], acc[mi][ni], 0, 0, 0);
                }
        }
    }

    const int r4 = (lane >> 4) * 4;
    #pragma unroll
    for (int mi = 0; mi < 2; ++mi)
        #pragma unroll
        for (int ni = 0; ni < 4; ++ni) {
            const int col = HID + bn * 128 + wn * 64 + ni * 16 + (lane & 15);
            #pragma unroll
            for (int r = 0; r < 4; ++r) {
                const int ml = wm * 32 + mi * 16 + r4 + r;
                if (bm * 64 + ml < n) {
                    const int t = s_node[ml];
                    Hbuf[(size_t)t * R5 + col] += acc[mi][ni][r];
                }
            }
        }
}

// ---------------------------------------------------------------------------
// Kernel 5 (per level): gates + cell update + output dist + argmax.
// Emits h as split-bf16 (hh/hl) for the next level's hgemm.
// ---------------------------------------------------------------------------
__global__ __launch_bounds__(256)
void level_gates(int lvl,
                 const int* __restrict__ level_start,
                 const int* __restrict__ level_nodes,
                 const int* __restrict__ proc_order,
                 const int* __restrict__ parent_pos,
                 const float* __restrict__ Hbuf,
                 const float* __restrict__ Xemb,
                 const float* __restrict__ W_out,
                 const float* __restrict__ b_out,
                 ushort* __restrict__ hh, ushort* __restrict__ hl,
                 float* __restrict__ c_all,
                 int* __restrict__ eidx_all,
                 float* __restrict__ out)
{
    const int s0 = level_start[lvl];
    const int n  = level_start[lvl + 1] - s0;
    const int tid = threadIdx.x;

    __shared__ __align__(16) float hs[HID];
    __shared__ float bv_s[4];
    __shared__ int   bi_s[4];

    for (int slot = blockIdx.x; slot < n; slot += gridDim.x) {
        const int t = level_nodes[s0 + slot];
        const int pid = parent_pos[t];
        const int eidx = (pid < 0) ? 0 : eidx_all[pid];

        const float4* H4 = (const float4*)(Hbuf + (size_t)t * R5);
        const float4* E4 = (const float4*)(Xemb + (size_t)eidx * R5);

        float4 Hpx = H4[tid],        Epx = E4[tid];
        float4 Hi  = H4[256 + tid],  Ei  = E4[256 + tid];
        float4 Ho  = H4[512 + tid],  Eo  = E4[512 + tid];
        float4 Hu  = H4[768 + tid],  Eu  = E4[768 + tid];
        float4 Hf  = H4[1024 + tid], Ef  = E4[1024 + tid];
        float4 PC = (pid < 0) ? make_float4(0.f, 0.f, 0.f, 0.f)
                              : ((const float4*)(c_all + (size_t)pid * HID))[tid];

        float cv[4], hv[4];
#define GATE(CP, IDX) { \
        float pxv = Hpx.CP + Epx.CP; \
        float iv  = Hi.CP + Ei.CP; \
        float ov  = Ho.CP + Eo.CP; \
        float uv  = Hu.CP + Eu.CP; \
        float fv  = Hf.CP + Ef.CP; \
        float ig = sigf(iv), og = sigf(ov), ug = tanhf(uv), fg = sigf(fv); \
        float cc = ig * ug + fg * PC.CP; \
        cv[IDX] = cc; \
        hv[IDX] = og * tanhf(cc) * sigf(pxv); }
        GATE(x, 0) GATE(y, 1) GATE(z, 2) GATE(w, 3)
#undef GATE

        float4 c4 = make_float4(cv[0], cv[1], cv[2], cv[3]);
        float4 h4 = make_float4(hv[0], hv[1], hv[2], hv[3]);
        ((float4*)(c_all + (size_t)t * HID))[tid] = c4;
        ((float4*)hs)[tid] = h4;
        ushort4 shi, slo;
        split2(h4.x, shi.x, slo.x); split2(h4.y, shi.y, slo.y);
        split2(h4.z, shi.z, slo.z); split2(h4.w, shi.w, slo.w);
        *(ushort4*)(hh + (size_t)t * HID + (tid << 2)) = shi;
        *(ushort4*)(hl + (size_t)t * HID + (tid << 2)) = slo;
        __syncthreads();

        const int node = proc_order[t];
        float* dists = out + (size_t)node * NCLS;
        const int wave = tid >> 6, lane = tid & 63;

        float bv = -3.4e38f; int bi = NCLS;
        for (int r = wave; r < NCLS; r += 4) {
            const float* wr = W_out + (size_t)r * HID;
            float s = 0.f;
            #pragma unroll
            for (int q = 0; q < 4; ++q) {
                float4 w4 = *(const float4*)(wr + (lane << 2) + q * 256);
                float4 x4 = *(const float4*)(hs + (lane << 2) + q * 256);
                s += w4.x * x4.x + w4.y * x4.y + w4.z * x4.z + w4.w * x4.w;
            }
            #pragma unroll
            for (int off = 32; off > 0; off >>= 1) s += __shfl_down(s, off, 64);
            if (lane == 0) {
                s += b_out[r];
                dists[r] = s;
                if (r >= 1 && s > bv) { bv = s; bi = r; }
            }
        }
        if (lane == 0) { bv_s[wave] = bv; bi_s[wave] = bi; }
        __syncthreads();
        if (tid == 0) {
            float v = bv_s[0]; int b = bi_s[0];
            for (int w = 1; w < 4; ++w) {
                if (bv_s[w] > v || (bv_s[w] == v && bi_s[w] < b)) { v = bv_s[w]; b = bi_s[w]; }
            }
            eidx_all[t] = b + 1;
            out[(size_t)N_OBJ * NCLS + node] = (float)b;
        }
        __syncthreads();   // hs / bv_s reused next slot
    }
}

// ---------------------------------------------------------------------------
extern "C" void kernel_launch(void* const* d_in, const int* in_sizes, int n_in,
                              void* d_out, int out_size, void* d_ws, size_t ws_size,
                              hipStream_t stream)
{
    const float* features = (const float*)d_in[0];
    const float* embed_W  = (const float*)d_in[1];
    const float* W_px     = (const float*)d_in[2];
    const float* b_px     = (const float*)d_in[3];
    const float* W_ioux   = (const float*)d_in[4];
    const float* b_ioux   = (const float*)d_in[5];
    const float* W_iouh   = (const float*)d_in[6];
    const float* b_iouh   = (const float*)d_in[7];
    const float* W_fx     = (const float*)d_in[8];
    const float* b_fx     = (const float*)d_in[9];
    const float* W_fh     = (const float*)d_in[10];
    const float* b_fh     = (const float*)d_in[11];
    const float* W_out    = (const float*)d_in[12];
    const float* b_out    = (const float*)d_in[13];
    const int* proc_order = (const int*)d_in[14];
    const int* parent_pos = (const int*)d_in[15];
    float* out = (float*)d_out;

    // workspace layout (~175 MB)
    float* Hbuf  = (float*)d_ws;                          // [N_OBJ][R5]
    float* c_all = Hbuf + (size_t)N_OBJ * R5;             // [N_OBJ][HID]
    float* Xemb  = c_all + (size_t)N_OBJ * HID;           // [NEMB][R5]
    ushort* Whh = (ushort*)(Xemb + (size_t)NEMB * R5);    // [RH][HID]
    ushort* Whl = Whh + (size_t)RH * HID;
    ushort* Wxh = Whl + (size_t)RH * HID;                 // [R5][IN_DIM]
    ushort* Wxl = Wxh + (size_t)R5 * IN_DIM;
    ushort* Fh  = Wxl + (size_t)R5 * IN_DIM;              // [N_OBJ][IN_DIM]
    ushort* Fl  = Fh + (size_t)N_OBJ * IN_DIM;
    ushort* hh  = Fl + (size_t)N_OBJ * IN_DIM;            // [N_OBJ][HID]
    ushort* hl  = hh + (size_t)N_OBJ * HID;
    ushort* zpad = hl + (size_t)N_OBJ * HID;              // [1024] zeros
    int* eidx_all    = (int*)(zpad + 1024);
    int* level_nodes = eidx_all + N_OBJ;
    int* level_start = level_nodes + N_OBJ;

    build_levels<<<1, 1024, 0, stream>>>(parent_pos, level_nodes, level_start, zpad);
    xemb_kernel<<<dim3(NEMB, R5 / 256), 256, 0, stream>>>(
        embed_W, W_px, W_ioux, W_fx, b_px, b_ioux, b_iouh, b_fx, b_fh, Xemb);
    convert_wh<<<RH * HID / 1024, 256, 0, stream>>>(W_iouh, W_fh, Whh, Whl);
    convert_wx<<<R5 * IN_DIM / 1024, 256, 0, stream>>>(W_px, W_ioux, W_fx, Wxh, Wxl);
    convert_f<<<N_OBJ * IN_DIM / 1024, 256, 0, stream>>>(features, proc_order, Fh, Fl);

    xgemm_mfma<<<(N_OBJ / 128) * (R5 / 128), 256, 0, stream>>>(Fh, Fl, Wxh, Wxl, Hbuf);

    level_gates<<<1024, 256, 0, stream>>>(
        0, level_start, level_nodes, proc_order, parent_pos,
        Hbuf, Xemb, W_out, b_out, hh, hl, c_all, eidx_all, out);

    for (int l = 1; l < MAXLVL; ++l) {
        hgemm_mfma<<<dim3(RH / 128, N_OBJ / 64), 256, 0, stream>>>(
            l, level_start, level_nodes, parent_pos, hh, hl, Whh, Whl, zpad, Hbuf);
        level_gates<<<1024, 256, 0, stream>>>(
            l, level_start, level_nodes, proc_order, parent_pos,
            Hbuf, Xemb, W_out, b_out, hh, hl, c_all, eidx_all, out);
    }
}